// Round 2
// baseline (132.045 us; speedup 1.0000x reference)
//
#include <hip/hip_runtime.h>

#define Hn 28
#define Wn 28
#define NI 128      // B*I = 8*16
#define PQ 784      // 28*28
#define SPAD 36     // sPart row stride (32 partials + pad, float4-aligned)

// tanh-form gelu: x * (1 - 1/(exp2(x*(k0 + k1*x^2)) + 1))
// k0 = 2*sqrt(2/pi)*log2(e) = 2.3022077, k1 = k0*0.044715 = 0.1029446
__device__ __forceinline__ float gelu_fast(float x) {
    const float x2 = x * x;
    const float u  = x * fmaf(x2, 0.1029446f, 2.3022077f);
    const float t  = __builtin_amdgcn_exp2f(u);
    const float r  = __builtin_amdgcn_rcpf(t + 1.0f);
    return fmaf(-x, r, x);   // x - x*r
}

// One block per (r,s). LDS = 14336 + 7168 + 18432 + 512 = 40448 B -> 4 blocks/CU.
__global__ __launch_bounds__(256, 4) void fused_kernel(
    const float* __restrict__ v, const float* __restrict__ W1,
    const float* __restrict__ b1, const float* __restrict__ W2,
    const float* __restrict__ b2, const float* __restrict__ bias,
    float* __restrict__ out)
{
    __shared__ float sVT[Hn * NI];       // [p][ni]   14336 B
    __shared__ float sH[Hn * 64];        // [p][c]     7168 B
    __shared__ float sPart[NI * SPAD];   // [no][32p] 18432 B
    __shared__ float sVsum[NI];          //             512 B

    const int t = threadIdx.x;
    const int rs = blockIdx.x;
    const int r = rs / Wn;
    const int s = rs - r * Wn;

    // ---- A. issue scattered loads of v[:, :, :, s] into registers (latency
    // hides under phase B). ni = t&127 is constant per thread; p = p0 + 2j.
    const int ni0 = t & 127;
    const int p0 = t >> 7;               // 0 or 1
    float vreg[14];
    #pragma unroll
    for (int j = 0; j < 14; ++j) {
        vreg[j] = v[ni0 * PQ + (p0 + 2 * j) * Wn + s];
    }

    // ---- B. sH[p][c] = sum_q gelu(xp*W1[0,c] + xq*W1[1,c] + xr*W1[2,c] + xs*W1[3,c] + b1[c])
    {
        const int c = t & 63;
        const int pg = t >> 6;           // 0..3, each does 7 p's
        const float w10 = W1[c];
        const float w11 = W1[64 + c];
        const float w12 = W1[128 + c];
        const float w13 = W1[192 + c];
        const float inv = 1.0f / 28.0f;
        const float base_rs = ((r + 0.5f) * inv) * w12 + ((s + 0.5f) * inv) * w13 + b1[c];
        const float w10i = inv * w10;
        const float w11i = inv * w11;
        #pragma unroll
        for (int pi = 0; pi < 7; ++pi) {
            const int p = pg * 7 + pi;
            const float base = fmaf((float)p + 0.5f, w10i, base_rs);
            float acc = 0.0f;
            #pragma unroll
            for (int q = 0; q < 28; ++q) {
                acc += gelu_fast(fmaf((float)q + 0.5f, w11i, base));
            }
            sH[p * 64 + c] = acc;
        }
    }

    // ---- A2. commit v registers to LDS (vmcnt wait lands here, after B)
    #pragma unroll
    for (int j = 0; j < 14; ++j) {
        sVT[(p0 + 2 * j) * NI + ni0] = vreg[j];
    }
    __syncthreads();

    // ---- C. column sums of the v slice (for the b2 term)
    if (t < NI) {
        float vs = 0.0f;
        #pragma unroll
        for (int p = 0; p < Hn; ++p) vs += sVT[p * NI + t];
        sVsum[t] = vs;
    }

    // ---- D. T-fragment: acc[k][j] = sum_p sVT[p][nig*8+k] * sH[p][cg*4+j]
    const int cg = t & 15;               // c = cg*4 .. cg*4+3
    const int nig = t >> 4;              // ni = nig*8 .. nig*8+7
    const int c0 = cg * 4;
    const int n = nig >> 1;              // batch index 0..7
    const int half = nig & 1;            // which 8-i half of n
    const int i0 = half * 8;

    float acc[8][4];
    #pragma unroll
    for (int k = 0; k < 8; ++k)
        #pragma unroll
        for (int j = 0; j < 4; ++j) acc[k][j] = 0.0f;

    #pragma unroll 4
    for (int p = 0; p < Hn; ++p) {
        const float4 h4 = *(const float4*)&sH[p * 64 + c0];
        const float4 va = *(const float4*)&sVT[p * NI + nig * 8];
        const float4 vb = *(const float4*)&sVT[p * NI + nig * 8 + 4];
        const float hh[4] = {h4.x, h4.y, h4.z, h4.w};
        const float vv[8] = {va.x, va.y, va.z, va.w, vb.x, vb.y, vb.z, vb.w};
        #pragma unroll
        for (int k = 0; k < 8; ++k)
            #pragma unroll
            for (int j = 0; j < 4; ++j)
                acc[k][j] += vv[k] * hh[j];
    }

    // ---- D2. contract fragment against W2 directly: for each o, partial
    // sum over (j<4 c's, k<8 i's); write to padded reduction buffer.
    #pragma unroll 2
    for (int o = 0; o < 16; ++o) {
        float sum = 0.0f;
        #pragma unroll
        for (int j = 0; j < 4; ++j) {
            const float* wrow = &W2[(c0 + j) * 256 + o * 16 + i0];
            const float4 w0 = *(const float4*)&wrow[0];
            const float4 w1 = *(const float4*)&wrow[4];
            sum += acc[0][j] * w0.x + acc[1][j] * w0.y + acc[2][j] * w0.z + acc[3][j] * w0.w
                 + acc[4][j] * w1.x + acc[5][j] * w1.y + acc[6][j] * w1.z + acc[7][j] * w1.w;
        }
        sPart[(n * 16 + o) * SPAD + cg * 2 + half] = sum;
    }
    __syncthreads();

    // ---- E. reduce 32 partials per output, add b2 term + bias, store.
    if (t < NI) {
        const int nn = t >> 4;
        const int oo = t & 15;
        const float* row = &sPart[t * SPAD];
        float tot = 0.0f;
        #pragma unroll
        for (int j = 0; j < 8; ++j) {
            const float4 pv = *(const float4*)&row[j * 4];
            tot += pv.x + pv.y + pv.z + pv.w;
        }
        float bsum = 0.0f;
        #pragma unroll
        for (int i4 = 0; i4 < 4; ++i4) {
            const float4 bv = *(const float4*)&b2[oo * 16 + i4 * 4];
            bsum += bv.x * sVsum[nn * 16 + i4 * 4 + 0]
                  + bv.y * sVsum[nn * 16 + i4 * 4 + 1]
                  + bv.z * sVsum[nn * 16 + i4 * 4 + 2]
                  + bv.w * sVsum[nn * 16 + i4 * 4 + 3];
        }
        const float quad = 1.0f / 784.0f;
        out[(nn * 16 + oo) * PQ + r * Wn + s] = quad * (tot + 28.0f * bsum) + bias[oo];
    }
}

extern "C" void kernel_launch(void* const* d_in, const int* in_sizes, int n_in,
                              void* d_out, int out_size, void* d_ws, size_t ws_size,
                              hipStream_t stream) {
    const float* v    = (const float*)d_in[0];  // (8,16,28,28)
    const float* W1   = (const float*)d_in[1];  // (4,64)
    const float* b1   = (const float*)d_in[2];  // (64,)
    const float* W2   = (const float*)d_in[3];  // (64,256)
    const float* b2   = (const float*)d_in[4];  // (256,)
    const float* bias = (const float*)d_in[5];  // (16,1,1)
    float* out = (float*)d_out;                 // (8,16,28,28) fp32

    fused_kernel<<<PQ, 256, 0, stream>>>(v, W1, b1, W2, b2, bias, out);
}

// Round 3
// 84.649 us; speedup vs baseline: 1.5599x; 1.5599x over previous
//
#include <hip/hip_runtime.h>

#define Hn 28
#define PQ 784     // 28*28
#define NI 128     // B*I

typedef __attribute__((ext_vector_type(8))) short short8v;   // 8 bf16 (4 VGPRs)
typedef __attribute__((ext_vector_type(4))) float float4v;   // MFMA C/D

__device__ __forceinline__ short f2bf(float x) {
    union { float f; unsigned u; } a; a.f = x;
    unsigned r = a.u + 0x7FFF + ((a.u >> 16) & 1);   // RNE
    return (short)(r >> 16);
}

// tanh-form gelu: x * (1 - 1/(exp2(x*(k0 + k1*x^2)) + 1))
__device__ __forceinline__ float gelu_fast(float x) {
    const float x2 = x * x;
    const float u  = x * fmaf(x2, 0.1029446f, 2.3022077f);
    const float t  = __builtin_amdgcn_exp2f(u);
    const float r  = __builtin_amdgcn_rcpf(t + 1.0f);
    return fmaf(-x, r, x);
}

// block ni<128: vTb[s][ni][p(pad32)] = bf16(v[ni][p][s]); Vsum[s][ni] = sum_p v.
// block 128: W2b = bf16(W2).
__global__ __launch_bounds__(256) void prep_kernel(
    const float* __restrict__ v, const float* __restrict__ W2,
    short* __restrict__ vTb, short* __restrict__ W2b, float* __restrict__ Vsum)
{
    const int b = blockIdx.x;
    const int t = threadIdx.x;
    if (b == NI) {   // W2 fp32 -> bf16, coalesced
        for (int e = t; e < 8192; e += 256) {
            const float2 f = ((const float2*)W2)[e];
            short2 h; h.x = f2bf(f.x); h.y = f2bf(f.y);
            ((short2*)W2b)[e] = h;
        }
        return;
    }
    const int ni = b;
    for (int e = t; e < PQ; e += 256) {   // coalesced read, scattered 2B write
        const int p = e / Hn;
        const int s = e - p * Hn;
        vTb[s * (NI * 32) + ni * 32 + p] = f2bf(v[ni * PQ + e]);
    }
    if (t < Hn) {   // zero p-pad 28..31 (8B store, 8-aligned)
        *(uint2*)(vTb + t * (NI * 32) + ni * 32 + 28) = make_uint2(0u, 0u);
    }
    if (t < Hn) {   // column sums for the b2 term
        const int s = t;
        float acc = 0.0f;
        #pragma unroll
        for (int p = 0; p < Hn; ++p) acc += v[ni * PQ + p * Hn + s];
        Vsum[s * NI + ni] = acc;
    }
}

// One block per (r,s). LDS = 10240+5120+16512+4096+512 = 36480 B -> 4 blocks/CU.
__global__ __launch_bounds__(256, 4) void fused_kernel(
    const short* __restrict__ vTb, const short* __restrict__ W2b,
    const float* __restrict__ Vsum,
    const float* __restrict__ W1, const float* __restrict__ b1,
    const float* __restrict__ b2, const float* __restrict__ bias,
    float* __restrict__ out)
{
    __shared__ short sV[NI * 40];       // [ni][p] pad40 bf16  10240 B
    __shared__ short sHt[64 * 40];      // [c][p]  pad40 bf16   5120 B
    __shared__ short sTa[8 * 1032];     // [n8][k=c*16+i] bf16 16512 B
    __shared__ float sRed[4 * 256];     // per-wave partials    4096 B
    __shared__ float sVs[NI];           //                       512 B

    const int t = threadIdx.x;
    const int rs = blockIdx.x;
    const int r = rs / Hn;
    const int s = rs - r * Hn;

    // ---- stage V slice: global [s][ni][p(32)] (contiguous 8KB) -> sV rows stride 40
    {
        const short* src = vTb + s * (NI * 32);
        #pragma unroll
        for (int j = 0; j < 2; ++j) {
            const int idx = t + 256 * j;       // 0..511
            const int ni = idx >> 2;
            const int ko = (idx & 3) * 8;
            *(short8v*)&sV[ni * 40 + ko] = *(const short8v*)(src + ni * 32 + ko);
        }
    }
    if (t < NI) sVs[t] = Vsum[s * NI + t];

    // ---- phase B: sHt[c][p] = bf16( sum_q gelu(...) ), zero p 28..31
    {
        const int c = t & 63;
        const int pg = t >> 6;               // 4 groups x 7 p
        const float w10 = W1[c];
        const float w11 = W1[64 + c];
        const float w12 = W1[128 + c];
        const float w13 = W1[192 + c];
        const float inv = 1.0f / 28.0f;
        const float base_rs = ((r + 0.5f) * inv) * w12 + ((s + 0.5f) * inv) * w13 + b1[c];
        const float w10i = inv * w10;
        const float w11i = inv * w11;
        #pragma unroll
        for (int pi = 0; pi < 7; ++pi) {
            const int p = pg * 7 + pi;
            const float base = fmaf((float)p + 0.5f, w10i, base_rs);
            float acc = 0.0f;
            #pragma unroll
            for (int q = 0; q < Hn; ++q) {
                acc += gelu_fast(fmaf((float)q + 0.5f, w11i, base));
            }
            sHt[c * 40 + p] = f2bf(acc);
        }
        if (pg == 3) *(uint2*)&sHt[c * 40 + 28] = make_uint2(0u, 0u);
    }
    __syncthreads();

    // ---- phase D (MFMA): T[ni][c] = sum_p V[ni][p] * H[p][c]
    const int w  = t >> 6;          // wave 0..3
    const int l  = t & 63;
    const int lm = l & 15;
    const int q  = l >> 4;
    const int k0 = q * 8;

    {
        short8v aF[2], bF[4];
        aF[0] = *(const short8v*)&sV[(32 * w + lm) * 40 + k0];
        aF[1] = *(const short8v*)&sV[(32 * w + 16 + lm) * 40 + k0];
        #pragma unroll
        for (int nt = 0; nt < 4; ++nt)
            bF[nt] = *(const short8v*)&sHt[(16 * nt + lm) * 40 + k0];

        float4v accD[2][4];
        #pragma unroll
        for (int mt = 0; mt < 2; ++mt)
            #pragma unroll
            for (int nt = 0; nt < 4; ++nt)
                accD[mt][nt] = __builtin_amdgcn_mfma_f32_16x16x32_bf16(
                    aF[mt], bF[nt], (float4v)(0.0f), 0, 0, 0);

        // scatter T to sTa[n8][c*16+i]: ni = 32w+16mt+q*4+reg -> n8=2w+mt, i=q*4+reg
        #pragma unroll
        for (int mt = 0; mt < 2; ++mt) {
            const int n8 = 2 * w + mt;
            #pragma unroll
            for (int nt = 0; nt < 4; ++nt) {
                const int c = 16 * nt + lm;
                #pragma unroll
                for (int reg = 0; reg < 4; ++reg) {
                    const int i = q * 4 + reg;
                    sTa[n8 * 1032 + c * 16 + i] = f2bf(accD[mt][nt][reg]);
                }
            }
        }
    }
    __syncthreads();

    // ---- phase D2 (MFMA): out[n8][o] = sum_k Ta[n8][k] * W2b[k][o], K=1024 split over waves
    float4v accO = (float4v)(0.0f);
    #pragma unroll
    for (int st = 0; st < 8; ++st) {
        const int kb = w * 256 + st * 32 + k0;
        const short8v a = *(const short8v*)&sTa[(lm & 7) * 1032 + kb];  // rows m>=8: dup, unused
        const int c  = kb >> 4;
        const int i0 = kb & 15;                                        // 0 or 8
        const short8v bfr = *(const short8v*)&W2b[c * 256 + lm * 16 + i0];
        accO = __builtin_amdgcn_mfma_f32_16x16x32_bf16(a, bfr, accO, 0, 0, 0);
    }
    #pragma unroll
    for (int reg = 0; reg < 4; ++reg) {
        const int m = q * 4 + reg;                 // 0..15, valid m<8
        sRed[w * 256 + m * 16 + lm] = accO[reg];
    }
    __syncthreads();

    // ---- E: reduce 4 wave-partials, add b2 term + bias, store
    if (t < NI) {
        const int n8 = t >> 4;
        const int o  = t & 15;
        const int e  = n8 * 16 + o;
        const float tot = sRed[e] + sRed[256 + e] + sRed[512 + e] + sRed[768 + e];
        float bsum = 0.0f;
        #pragma unroll
        for (int i = 0; i < 16; ++i)
            bsum = fmaf(b2[o * 16 + i], sVs[n8 * 16 + i], bsum);
        out[(n8 * 16 + o) * PQ + rs] = (tot + 28.0f * bsum) * (1.0f / 784.0f) + bias[o];
    }
}

extern "C" void kernel_launch(void* const* d_in, const int* in_sizes, int n_in,
                              void* d_out, int out_size, void* d_ws, size_t ws_size,
                              hipStream_t stream) {
    const float* v    = (const float*)d_in[0];  // (8,16,28,28)
    const float* W1   = (const float*)d_in[1];  // (4,64)
    const float* b1   = (const float*)d_in[2];  // (64,)
    const float* W2   = (const float*)d_in[3];  // (64,256)
    const float* b2   = (const float*)d_in[4];  // (256,)
    const float* bias = (const float*)d_in[5];  // (16,1,1)
    float* out = (float*)d_out;                 // (8,16,28,28) fp32

    char* ws = (char*)d_ws;
    short* vTb  = (short*)(ws);                 // 28*128*32*2 = 229376 B
    short* W2b  = (short*)(ws + 229376);        // 16384*2     =  32768 B
    float* Vsum = (float*)(ws + 262144);        // 28*128*4    =  14336 B

    prep_kernel<<<NI + 1, 256, 0, stream>>>(v, W2, vTb, W2b, Vsum);
    fused_kernel<<<PQ, 256, 0, stream>>>(vTb, W2b, Vsum, W1, b1, b2, bias, out);
}